// Round 8
// baseline (66.725 us; speedup 1.0000x reference)
//
#include <hip/hip_runtime.h>
#include <math.h>

#define CLIPV 0.03f

struct W9 { float g[9]; };

__device__ __forceinline__ int reflect_idx(int i, int n) {
    if (i < 0) i = -i;
    if (i >= n) i = 2 * n - 2 - i;
    return i;
}

// ---------------------------------------------------------------------------
// Pass A: H-conv only (unchanged from R7 — measured at the streaming floor).
// One wave = (z-plane, 16-row h-chunk); lane owns 4 consecutive cols.
// 9-deep raw-row f4 ring, 2-deep load pipeline, zero LDS/cross-lane/barriers.
// ---------------------------------------------------------------------------
__global__ __launch_bounds__(256) void h_pass(const float* __restrict__ x,
                                              float* __restrict__ tmp, W9 wt) {
    const int bid = blockIdx.x;
    const int xcd = bid & 7;
    const int k   = bid >> 3;              // 0..127
    const int z   = xcd * 32 + (k >> 2);   // XCD-local z band
    const int q   = k & 3;
    const int wv  = threadIdx.x >> 6;
    const int h0  = (q * 4 + wv) * 16;     // this wave's 16 output rows
    const int w4  = (threadIdx.x & 63) * 4;

    const float* plane  = x   + (size_t)z * 65536;
    float*       oplane = tmp + (size_t)z * 65536;

    float4 ring[9];

    float4 cur = *(const float4*)(plane + reflect_idx(h0 - 4, 256) * 256 + w4);
    float4 nxt = *(const float4*)(plane + reflect_idx(h0 - 3, 256) * 256 + w4);

    #pragma unroll
    for (int i = 0; i < 24; ++i) {
        float4 nn;
        if (i < 22)
            nn = *(const float4*)(plane + reflect_idx(h0 - 2 + i, 256) * 256 + w4);

        ring[i % 9] = cur;

        if (i >= 8) {
            float a0 = 0.f, a1 = 0.f, a2 = 0.f, a3 = 0.f;
            #pragma unroll
            for (int j = 0; j < 9; ++j) {
                const float4 v = ring[(i - 8 + j) % 9];
                a0 = fmaf(wt.g[j], v.x, a0);
                a1 = fmaf(wt.g[j], v.y, a1);
                a2 = fmaf(wt.g[j], v.z, a2);
                a3 = fmaf(wt.g[j], v.w, a3);
            }
            float4 o; o.x = a0; o.y = a1; o.z = a2; o.w = a3;
            *(float4*)(oplane + (h0 + i - 8) * 256 + w4) = o;
        }

        cur = nxt; nxt = nn;
    }
}

// ---------------------------------------------------------------------------
// Pass B: W-conv + D-conv + clip, fused, with an explicit 1-iteration
// software pipeline: the 3 overlapping tmp f4 loads AND the clip-source x f4
// for step i+1 are issued before the compute of step i (full unroll =>
// registers renamed; ~1 iteration x 4 waves of compute covers L3 latency).
// One wave = (row h, 16-plane z-chunk); lane owns 4 consecutive cols.
// Grid: 1024 blocks x 4 waves = 4096 waves; chunk->XCD matches pass A.
// ---------------------------------------------------------------------------
__global__ __launch_bounds__(256) void wd_clip_pass(const float* __restrict__ tmp,
                                                    const float* __restrict__ x,
                                                    float* __restrict__ out, W9 wt) {
    const int bid = blockIdx.x;
    const int xcd = bid & 7;
    const int k   = bid >> 3;                       // 0..127
    const int h   = (k >> 1) * 4 + (threadIdx.x >> 6);
    const int z0  = (xcd * 2 + (k & 1)) * 16;       // XCD-local z-chunk
    const int L   = threadIdx.x & 63;
    const int w4  = L * 4;
    const bool l0 = (L == 0), l63 = (L == 63);
    // lane 0: cols -4..-1 reflect-> 4,3,2,1: load f4 at 1, use reversed.
    // lane 63: cols 256..259 reflect-> 254..251: load f4 at 251, reversed.
    const int offL = l0 ? 1 : (w4 - 4);
    const int offR = l63 ? 251 : (w4 + 4);

    const size_t rowoff = (size_t)h * 256;

    float4 ring[9];

    // prime the pipeline: loads for step 0
    float4 cL, cC, cR, cX;
    {
        const float* trow = tmp + (size_t)reflect_idx(z0 - 4, 256) * 65536 + rowoff;
        cL = *(const float4*)(trow + offL);
        cC = *(const float4*)(trow + w4);
        cR = *(const float4*)(trow + offR);
    }

    #pragma unroll
    for (int i = 0; i < 24; ++i) {
        // ---- issue step i+1 loads (consumed next iteration) ----
        float4 nL, nC, nR, nX;
        if (i < 23) {
            const float* trow =
                tmp + (size_t)reflect_idx(z0 - 3 + i, 256) * 65536 + rowoff;
            nL = *(const float4*)(trow + offL);
            nC = *(const float4*)(trow + w4);
            nR = *(const float4*)(trow + offR);
            if (i + 1 >= 8)
                nX = *(const float4*)(x + (size_t)(z0 + i - 7) * 65536 + rowoff + w4);
        }

        // ---- W-conv for step i (plane z0-4+i) ----
        float sv[12];
        sv[0] = l0 ? cL.w : cL.x;   // col -4 -> 4
        sv[1] = l0 ? cL.z : cL.y;   // col -3 -> 3
        sv[2] = l0 ? cL.y : cL.z;   // col -2 -> 2
        sv[3] = l0 ? cL.x : cL.w;   // col -1 -> 1
        sv[4] = cC.x; sv[5] = cC.y; sv[6] = cC.z; sv[7] = cC.w;
        sv[8]  = l63 ? cR.w : cR.x; // col 256 -> 254
        sv[9]  = l63 ? cR.z : cR.y; // col 257 -> 253
        sv[10] = l63 ? cR.y : cR.z; // col 258 -> 252
        sv[11] = l63 ? cR.x : cR.w; // col 259 -> 251

        float4 wc;
        {
            float a0 = 0.f, a1 = 0.f, a2 = 0.f, a3 = 0.f;
            #pragma unroll
            for (int j = 0; j < 9; ++j) {
                a0 = fmaf(wt.g[j], sv[j],     a0);
                a1 = fmaf(wt.g[j], sv[j + 1], a1);
                a2 = fmaf(wt.g[j], sv[j + 2], a2);
                a3 = fmaf(wt.g[j], sv[j + 3], a3);
            }
            wc.x = a0; wc.y = a1; wc.z = a2; wc.w = a3;
        }
        ring[i % 9] = wc;   // static index after unroll

        // ---- D-conv + clip + store ----
        if (i >= 8) {
            const int z = z0 + i - 8;
            float a0 = 0.f, a1 = 0.f, a2 = 0.f, a3 = 0.f;
            #pragma unroll
            for (int j = 0; j < 9; ++j) {
                const float4 v = ring[(i - 8 + j) % 9];
                a0 = fmaf(wt.g[j], v.x, a0);
                a1 = fmaf(wt.g[j], v.y, a1);
                a2 = fmaf(wt.g[j], v.z, a2);
                a3 = fmaf(wt.g[j], v.w, a3);
            }
            float4 r;
            r.x = fmaxf(fminf(cX.x, a0 + CLIPV), a0 - CLIPV);
            r.y = fmaxf(fminf(cX.y, a1 + CLIPV), a1 - CLIPV);
            r.z = fmaxf(fminf(cX.z, a2 + CLIPV), a2 - CLIPV);
            r.w = fmaxf(fminf(cX.w, a3 + CLIPV), a3 - CLIPV);
            *(float4*)(out + (size_t)z * 65536 + rowoff + w4) = r;
        }

        cL = nL; cC = nC; cR = nR; cX = nX;
    }
}

extern "C" void kernel_launch(void* const* d_in, const int* in_sizes, int n_in,
                              void* d_out, int out_size, void* d_ws, size_t ws_size,
                              hipStream_t stream) {
    const float* x = (const float*)d_in[0];
    float* out = (float*)d_out;
    float* tmp = (float*)d_ws;   // 64 MB

    // normalized 1-D Gaussian weights (separable form of the reference kernel)
    W9 wt;
    {
        double g[9], s = 0.0;
        const double sigma = 9.0 / 4.0;
        for (int i = 0; i < 9; ++i) {
            double tt = (i - 4.0) / sigma;
            g[i] = exp(-0.5 * tt * tt);
            s += g[i];
        }
        for (int i = 0; i < 9; ++i) wt.g[i] = (float)(g[i] / s);
    }

    h_pass<<<dim3(1024), dim3(256), 0, stream>>>(x, tmp, wt);
    wd_clip_pass<<<dim3(1024), dim3(256), 0, stream>>>(tmp, x, out, wt);
}

// Round 9
// 55.735 us; speedup vs baseline: 1.1972x; 1.1972x over previous
//
#include <hip/hip_runtime.h>
#include <hip/hip_fp16.h>
#include <math.h>

#define CLIPV 0.03f

struct W9 { float g[9]; };
struct half4 { __half2 a, b; };   // 8 bytes, 2 VGPRs

__device__ __forceinline__ int reflect_idx(int i, int n) {
    if (i < 0) i = -i;
    if (i >= n) i = 2 * n - 2 - i;
    return i;
}

// ---------------------------------------------------------------------------
// Pass A: H-conv only (R7 structure, fp16 output).
// One wave = (z-plane, 16-row h-chunk); lane owns 4 consecutive cols.
// 9-deep raw-row f4 ring, 2-deep load pipeline, zero LDS/cross-lane/barriers.
// Stores half4 (8 B/lane). Grid: 1024 blocks x 4 waves (16 waves/CU).
// ---------------------------------------------------------------------------
__global__ __launch_bounds__(256) void h_pass(const float* __restrict__ x,
                                              __half* __restrict__ tmp, W9 wt) {
    const int bid = blockIdx.x;
    const int xcd = bid & 7;
    const int k   = bid >> 3;              // 0..127
    const int z   = xcd * 32 + (k >> 2);   // XCD-local z band
    const int q   = k & 3;
    const int wv  = threadIdx.x >> 6;
    const int h0  = (q * 4 + wv) * 16;     // this wave's 16 output rows
    const int w4  = (threadIdx.x & 63) * 4;

    const float* plane  = x   + (size_t)z * 65536;
    __half*      oplane = tmp + (size_t)z * 65536;

    float4 ring[9];

    float4 cur = *(const float4*)(plane + reflect_idx(h0 - 4, 256) * 256 + w4);
    float4 nxt = *(const float4*)(plane + reflect_idx(h0 - 3, 256) * 256 + w4);

    #pragma unroll
    for (int i = 0; i < 24; ++i) {
        float4 nn;
        if (i < 22)
            nn = *(const float4*)(plane + reflect_idx(h0 - 2 + i, 256) * 256 + w4);

        ring[i % 9] = cur;

        if (i >= 8) {
            float a0 = 0.f, a1 = 0.f, a2 = 0.f, a3 = 0.f;
            #pragma unroll
            for (int j = 0; j < 9; ++j) {
                const float4 v = ring[(i - 8 + j) % 9];
                a0 = fmaf(wt.g[j], v.x, a0);
                a1 = fmaf(wt.g[j], v.y, a1);
                a2 = fmaf(wt.g[j], v.z, a2);
                a3 = fmaf(wt.g[j], v.w, a3);
            }
            half4 o;
            o.a = __floats2half2_rn(a0, a1);
            o.b = __floats2half2_rn(a2, a3);
            *(half4*)(oplane + (size_t)(h0 + i - 8) * 256 + w4) = o;
        }

        cur = nxt; nxt = nn;
    }
}

// ---------------------------------------------------------------------------
// Pass B: W-conv + D-conv + clip on fp16 tmp, 1-deep software pipeline.
// One wave = (row h, 8-plane z-chunk); lane owns 4 consecutive cols.
// Per z-step: 3 half4 loads of tmp (L1/L2-hot; edge lanes use the R6 select
// table with dummy-aligned L/R loads), W-conv (36 FMA) -> 9-deep f32 z-ring
// -> D-conv (36 FMA) + clip vs x + f4 store.
// Grid: 2048 blocks x 4 waves = 8192 waves = 32 waves/CU (not grid-capped).
// Chunk->XCD mapping matches pass A's writer band.
// ---------------------------------------------------------------------------
__global__ __launch_bounds__(256) void wd_clip_pass(const __half* __restrict__ tmp,
                                                    const float* __restrict__ x,
                                                    float* __restrict__ out, W9 wt) {
    const int bid = blockIdx.x;
    const int xcd = bid & 7;
    const int r   = bid >> 3;                        // 0..255
    const int h   = (r >> 2) * 4 + (threadIdx.x >> 6);
    const int z0  = xcd * 32 + (r & 3) * 8;          // XCD-local z-chunk of 8
    const int L   = threadIdx.x & 63;
    const int w4  = L * 4;
    const bool l0 = (L == 0), l63 = (L == 63);
    // Edge lanes: L/R loads are dummies at aligned safe offsets; reflected
    // values come from C/L/R via the select table below (validated in R6).
    const int offL = l0 ? w4 : (w4 - 4);
    const int offR = l63 ? w4 : (w4 + 4);

    const size_t rowoff = (size_t)h * 256;

    float4 ring[9];

    // prime the pipeline: loads for step 0
    half4 cL, cC, cR; float4 cX;
    {
        const __half* trow = tmp + (size_t)reflect_idx(z0 - 4, 256) * 65536 + rowoff;
        cL = *(const half4*)(trow + offL);
        cC = *(const half4*)(trow + w4);
        cR = *(const half4*)(trow + offR);
    }

    #pragma unroll
    for (int i = 0; i < 16; ++i) {
        // ---- issue step i+1 loads (consumed next iteration) ----
        half4 nL, nC, nR; float4 nX;
        if (i < 15) {
            const __half* trow =
                tmp + (size_t)reflect_idx(z0 - 3 + i, 256) * 65536 + rowoff;
            nL = *(const half4*)(trow + offL);
            nC = *(const half4*)(trow + w4);
            nR = *(const half4*)(trow + offR);
            if (i >= 7)
                nX = *(const float4*)(x + (size_t)(z0 + i - 7) * 65536 + rowoff + w4);
        }

        // ---- unpack to f32 ----
        const float2 Lab = __half22float2(cL.a), Lcd = __half22float2(cL.b);
        const float2 Cab = __half22float2(cC.a), Ccd = __half22float2(cC.b);
        const float2 Rab = __half22float2(cR.a), Rcd = __half22float2(cR.b);
        const float Lx = Lab.x, Ly = Lab.y, Lz = Lcd.x, Lw = Lcd.y;
        const float Cx = Cab.x, Cy = Cab.y, Cz = Ccd.x, Cw = Ccd.y;
        const float Rx = Rab.x, Ry = Rab.y, Rz = Rcd.x, Rw = Rcd.y;

        // ---- W-window with reflect selects (R6 table) ----
        float sv[12];
        sv[0] = l0 ? Rx : Lx;   // col -4 -> 4
        sv[1] = l0 ? Cw : Ly;   // col -3 -> 3
        sv[2] = l0 ? Cz : Lz;   // col -2 -> 2
        sv[3] = l0 ? Cy : Lw;   // col -1 -> 1
        sv[4] = Cx; sv[5] = Cy; sv[6] = Cz; sv[7] = Cw;
        sv[8]  = l63 ? Cz : Rx; // col 256 -> 254
        sv[9]  = l63 ? Cy : Ry; // col 257 -> 253
        sv[10] = l63 ? Cx : Rz; // col 258 -> 252
        sv[11] = l63 ? Lw : Rw; // col 259 -> 251

        // ---- W-conv -> one float4 (this z-plane) ----
        float4 wc;
        {
            float a0 = 0.f, a1 = 0.f, a2 = 0.f, a3 = 0.f;
            #pragma unroll
            for (int j = 0; j < 9; ++j) {
                a0 = fmaf(wt.g[j], sv[j],     a0);
                a1 = fmaf(wt.g[j], sv[j + 1], a1);
                a2 = fmaf(wt.g[j], sv[j + 2], a2);
                a3 = fmaf(wt.g[j], sv[j + 3], a3);
            }
            wc.x = a0; wc.y = a1; wc.z = a2; wc.w = a3;
        }
        ring[i % 9] = wc;   // static index after full unroll

        // ---- D-conv + clip + store ----
        if (i >= 8) {
            const int z = z0 + i - 8;
            float a0 = 0.f, a1 = 0.f, a2 = 0.f, a3 = 0.f;
            #pragma unroll
            for (int j = 0; j < 9; ++j) {
                const float4 v = ring[(i - 8 + j) % 9];
                a0 = fmaf(wt.g[j], v.x, a0);
                a1 = fmaf(wt.g[j], v.y, a1);
                a2 = fmaf(wt.g[j], v.z, a2);
                a3 = fmaf(wt.g[j], v.w, a3);
            }
            float4 rr;
            rr.x = fmaxf(fminf(cX.x, a0 + CLIPV), a0 - CLIPV);
            rr.y = fmaxf(fminf(cX.y, a1 + CLIPV), a1 - CLIPV);
            rr.z = fmaxf(fminf(cX.z, a2 + CLIPV), a2 - CLIPV);
            rr.w = fmaxf(fminf(cX.w, a3 + CLIPV), a3 - CLIPV);
            *(float4*)(out + (size_t)z * 65536 + rowoff + w4) = rr;
        }

        cL = nL; cC = nC; cR = nR; cX = nX;
    }
}

extern "C" void kernel_launch(void* const* d_in, const int* in_sizes, int n_in,
                              void* d_out, int out_size, void* d_ws, size_t ws_size,
                              hipStream_t stream) {
    const float* x = (const float*)d_in[0];
    float* out = (float*)d_out;
    __half* tmp = (__half*)d_ws;   // 32 MB (fp16)

    // normalized 1-D Gaussian weights (separable form of the reference kernel)
    W9 wt;
    {
        double g[9], s = 0.0;
        const double sigma = 9.0 / 4.0;
        for (int i = 0; i < 9; ++i) {
            double tt = (i - 4.0) / sigma;
            g[i] = exp(-0.5 * tt * tt);
            s += g[i];
        }
        for (int i = 0; i < 9; ++i) wt.g[i] = (float)(g[i] / s);
    }

    h_pass<<<dim3(1024), dim3(256), 0, stream>>>(x, tmp, wt);
    wd_clip_pass<<<dim3(2048), dim3(256), 0, stream>>>(tmp, x, out, wt);
}